// Round 3
// baseline (54400.360 us; speedup 1.0000x reference)
//
#include <hip/hip_runtime.h>
#include <cstddef>
#include <cstdint>

#define NOBJ 50000
#define NTRI 250000

typedef _Float16 f16;
typedef _Float16 f16x8 __attribute__((ext_vector_type(8)));
typedef float f32x4 __attribute__((ext_vector_type(4)));

__device__ __forceinline__ float leaky(float x) { return x > 0.0f ? x : 0.2f * x; }
__device__ __forceinline__ void fsplit(float y, f16& h, f16& l) {
    h = (f16)y;
    l = (f16)(y - (float)h);
}

// ---------------------------------------------------------------------------
// Embedding: obj = leaky([obj_vecs | boxes] @ W_emb + b_emb) -> hi/lo f16, stride 64
// ---------------------------------------------------------------------------
__global__ __launch_bounds__(256) void embed_kernel(
    const float* __restrict__ obj_vecs, const float* __restrict__ boxes,
    const float* __restrict__ W, const float* __restrict__ b,
    f16* __restrict__ oh, f16* __restrict__ ol)
{
    __shared__ float Ws[68 * 64];
    const int tid = threadIdx.x;
    for (int i = tid; i < 68 * 64; i += 256) Ws[i] = W[i];
    __syncthreads();
    const int row = blockIdx.x * 4 + (tid >> 6);
    const int col = tid & 63;
    if (row >= NOBJ) return;
    float acc = b[col];
    const float* __restrict__ a = obj_vecs + (size_t)row * 64;
#pragma unroll 16
    for (int k = 0; k < 64; ++k) acc = fmaf(a[k], Ws[k * 64 + col], acc);
    const float* __restrict__ bx = boxes + (size_t)row * 4;
#pragma unroll
    for (int k = 0; k < 4; ++k) acc = fmaf(bx[k], Ws[(64 + k) * 64 + col], acc);
    f16 h, l;
    fsplit(leaky(acc), h, l);
    oh[(size_t)row * 64 + col] = h;
    ol[(size_t)row * 64 + col] = l;
}

// ---------------------------------------------------------------------------
// Weight transpose + split: W[K][N] f32 -> Th/Tl[N][K] f16
// ---------------------------------------------------------------------------
__global__ __launch_bounds__(256) void tsplit_kernel(
    const float* __restrict__ W, int K, int N,
    f16* __restrict__ Th, f16* __restrict__ Tl)
{
    __shared__ float T[64][65];
    const int n0 = blockIdx.x * 64, k0 = blockIdx.y * 64;
    const int tc = threadIdx.x & 63, tr = threadIdx.x >> 6;
    for (int r = tr; r < 64; r += 4) {
        const int k = k0 + r, n = n0 + tc;
        T[r][tc] = (k < K && n < N) ? W[(size_t)k * N + n] : 0.0f;
    }
    __syncthreads();
    for (int r = tr; r < 64; r += 4) {
        const int n = n0 + r, k = k0 + tc;
        if (n < N && k < K) {
            f16 h, l;
            fsplit(T[tc][r], h, l);
            Th[(size_t)n * K + k] = h;
            Tl[(size_t)n * K + k] = l;
        }
    }
}

// ---------------------------------------------------------------------------
// Degree counts, then invert
// ---------------------------------------------------------------------------
__global__ __launch_bounds__(256) void count_kernel(
    const int* __restrict__ s, const int* __restrict__ o, float* __restrict__ cnt)
{
    const int t = blockIdx.x * 256 + threadIdx.x;
    if (t < NTRI) {
        atomicAdd(&cnt[s[t]], 1.0f);
        atomicAdd(&cnt[o[t]], 1.0f);
    }
}

__global__ __launch_bounds__(256) void invcnt_kernel(float* __restrict__ cnt)
{
    const int i = blockIdx.x * 256 + threadIdx.x;
    if (i < NOBJ) cnt[i] = 1.0f / fmaxf(cnt[i], 1.0f);
}

enum { AM_PLAIN = 0, AM_GATHER = 1, AM_SCALED = 2 };
enum { EP_STORE = 0, EP_SPLIT = 1, EP_STORE16 = 2 };

// ---------------------------------------------------------------------------
// Split-f16 MFMA GEMM: C = A @ Wt^T, 128x128 tile, K-step 32, 4 waves (2x2 of 64x64).
// A and B are (hi,lo) f16 pairs; 3 MFMA passes per fragment (hi*hi+hi*lo+lo*hi).
// MFMA 16x16x32 f16: A-frag lane: row=lane&15, k=8*(lane>>4)+e (contiguous 8 f16);
// B stored transposed in LDS (Bt[col][k]) so B-frag is the same contiguous read.
// C/D: row=(lane>>4)*4+reg, col=lane&15  [m89-verified].
// ---------------------------------------------------------------------------
template <int AMODE, int EPMODE, int DIN, int K, int H, int DOUT, int NTOT, int PRED32>
__global__ __launch_bounds__(256, 2) void mgemm_kernel(
    const f16* __restrict__ A0h, const f16* __restrict__ A0l,   // obj (gather) or hid (plain)
    const f16* __restrict__ A1h, const f16* __restrict__ A1l,   // pred f16 (layers>=1)
    const float* __restrict__ A1f,                              // pred f32 (layer0)
    const int* __restrict__ sidx, const int* __restrict__ oidx,
    const f16* __restrict__ Bth, const f16* __restrict__ Btl,   // Wt [NTOT][K]
    const float* __restrict__ bias,
    float* __restrict__ C0,                                     // EP_SPLIT: pooled f32
    f16* __restrict__ D0h, f16* __restrict__ D0l,               // EP_STORE: hid ; EP_SPLIT: pred
    int M)
{
    constexpr int LDT = 40;  // 32 + 8 pad: 80B rows -> 16B aligned, ~2-way banks
    __shared__ f16 Ah[128][LDT], Al[128][LDT], Bh[128][LDT], Bl[128][LDT];

    const int tid = threadIdx.x;
    const int wave = tid >> 6, lane = tid & 63;
    const int l16 = lane & 15, lq = lane >> 4;
    const int m0 = blockIdx.x * 128, n0 = blockIdx.y * 128;
    const int wr = (wave >> 1) * 64, wc = (wave & 1) * 64;

    f32x4 acc[4][4];
    const f32x4 zz = {0.0f, 0.0f, 0.0f, 0.0f};
#pragma unroll
    for (int i = 0; i < 4; ++i)
#pragma unroll
        for (int j = 0; j < 4; ++j) acc[i][j] = zz;

    // staging: 2 threads per row, each covers 16 k-elements
    const int arow = tid >> 1;
    const int koff = (tid & 1) * 16;
    int am = m0 + arow;
    if (am > M - 1) am = M - 1;          // clamp tail (stores guarded)
    int asrow = 0, aorow = 0;
    if (AMODE == AM_GATHER) { asrow = sidx[am]; aorow = oidx[am]; }
    const size_t bwrow = (size_t)(n0 + arow) * K;

#pragma unroll 1
    for (int k0 = 0; k0 < K; k0 += 32) {
        __syncthreads();
        // ---- stage A ----
        bool f32path = false;
        const f16 *sh = nullptr, *sl = nullptr;
        const float* sf = nullptr;
        if (AMODE == AM_GATHER) {
            if (k0 < DIN) {
                sh = A0h + (size_t)asrow * DIN + k0;
                sl = A0l + (size_t)asrow * DIN + k0;
            } else if (k0 < 2 * DIN) {
                if (PRED32) { sf = A1f + (size_t)am * DIN + (k0 - DIN); f32path = true; }
                else {
                    sh = A1h + (size_t)am * DIN + (k0 - DIN);
                    sl = A1l + (size_t)am * DIN + (k0 - DIN);
                }
            } else {
                sh = A0h + (size_t)aorow * DIN + (k0 - 2 * DIN);
                sl = A0l + (size_t)aorow * DIN + (k0 - 2 * DIN);
            }
        } else {
            sh = A0h + (size_t)am * K + k0;
            sl = A0l + (size_t)am * K + k0;
        }
        if (PRED32 && f32path) {
            float v[16];
#pragma unroll
            for (int q = 0; q < 4; ++q)
                *reinterpret_cast<float4*>(&v[q * 4]) = *reinterpret_cast<const float4*>(sf + koff + q * 4);
            f16 hh[16], ll[16];
#pragma unroll
            for (int e = 0; e < 16; ++e) fsplit(v[e], hh[e], ll[e]);
#pragma unroll
            for (int q = 0; q < 2; ++q) {
                *reinterpret_cast<f16x8*>(&Ah[arow][koff + q * 8]) = *reinterpret_cast<f16x8*>(&hh[q * 8]);
                *reinterpret_cast<f16x8*>(&Al[arow][koff + q * 8]) = *reinterpret_cast<f16x8*>(&ll[q * 8]);
            }
        } else {
#pragma unroll
            for (int q = 0; q < 2; ++q) {
                *reinterpret_cast<f16x8*>(&Ah[arow][koff + q * 8]) = *reinterpret_cast<const f16x8*>(sh + koff + q * 8);
                *reinterpret_cast<f16x8*>(&Al[arow][koff + q * 8]) = *reinterpret_cast<const f16x8*>(sl + koff + q * 8);
            }
        }
        // ---- stage B (Wt rows = output cols) ----
#pragma unroll
        for (int q = 0; q < 2; ++q) {
            *reinterpret_cast<f16x8*>(&Bh[arow][koff + q * 8]) = *reinterpret_cast<const f16x8*>(Bth + bwrow + k0 + koff + q * 8);
            *reinterpret_cast<f16x8*>(&Bl[arow][koff + q * 8]) = *reinterpret_cast<const f16x8*>(Btl + bwrow + k0 + koff + q * 8);
        }
        __syncthreads();
        // ---- fragments + MFMA ----
        f16x8 fah[4], fal[4], fbh[4], fbl[4];
#pragma unroll
        for (int fi = 0; fi < 4; ++fi) {
            const int r = wr + fi * 16 + l16;
            fah[fi] = *reinterpret_cast<const f16x8*>(&Ah[r][lq * 8]);
            fal[fi] = *reinterpret_cast<const f16x8*>(&Al[r][lq * 8]);
        }
#pragma unroll
        for (int fj = 0; fj < 4; ++fj) {
            const int c = wc + fj * 16 + l16;
            fbh[fj] = *reinterpret_cast<const f16x8*>(&Bh[c][lq * 8]);
            fbl[fj] = *reinterpret_cast<const f16x8*>(&Bl[c][lq * 8]);
        }
#pragma unroll
        for (int fi = 0; fi < 4; ++fi)
#pragma unroll
            for (int fj = 0; fj < 4; ++fj) {
                acc[fi][fj] = __builtin_amdgcn_mfma_f32_16x16x32_f16(fah[fi], fbh[fj], acc[fi][fj], 0, 0, 0);
                acc[fi][fj] = __builtin_amdgcn_mfma_f32_16x16x32_f16(fah[fi], fbl[fj], acc[fi][fj], 0, 0, 0);
                acc[fi][fj] = __builtin_amdgcn_mfma_f32_16x16x32_f16(fal[fi], fbh[fj], acc[fi][fj], 0, 0, 0);
            }
    }

    // ---- epilogue ----
    float bb[4];
#pragma unroll
    for (int fj = 0; fj < 4; ++fj) bb[fj] = bias[n0 + wc + fj * 16 + l16];

    if (EPMODE == EP_STORE) {
#pragma unroll
        for (int fi = 0; fi < 4; ++fi)
#pragma unroll
            for (int r = 0; r < 4; ++r) {
                const int rowg = m0 + wr + fi * 16 + lq * 4 + r;
                if (rowg >= M) continue;
#pragma unroll
                for (int fj = 0; fj < 4; ++fj) {
                    const int col = n0 + wc + fj * 16 + l16;
                    f16 h, l;
                    fsplit(leaky(acc[fi][fj][r] + bb[fj]), h, l);
                    D0h[(size_t)rowg * NTOT + col] = h;
                    D0l[(size_t)rowg * NTOT + col] = l;
                }
            }
    } else {
        constexpr int SCH = H / 128;
        const int chunk = blockIdx.y;
#pragma unroll
        for (int fi = 0; fi < 4; ++fi)
#pragma unroll
            for (int r = 0; r < 4; ++r) {
                const int rowg = m0 + wr + fi * 16 + lq * 4 + r;
                if (rowg >= M) continue;
                if (chunk < SCH) {
                    const int t = sidx[rowg];
                    float* dst = C0 + (size_t)t * H;
#pragma unroll
                    for (int fj = 0; fj < 4; ++fj) {
                        const int col = n0 + wc + fj * 16 + l16;
                        atomicAdd(dst + col, leaky(acc[fi][fj][r] + bb[fj]));
                    }
                } else if (chunk == SCH) {
#pragma unroll
                    for (int fj = 0; fj < 4; ++fj) {
                        const int col = n0 + wc + fj * 16 + l16 - H;
                        f16 h, l;
                        fsplit(leaky(acc[fi][fj][r] + bb[fj]), h, l);
                        D0h[(size_t)rowg * DOUT + col] = h;
                        D0l[(size_t)rowg * DOUT + col] = l;
                    }
                } else {
                    const int t = oidx[rowg];
                    float* dst = C0 + (size_t)t * H;
#pragma unroll
                    for (int fj = 0; fj < 4; ++fj) {
                        const int col = n0 + wc + fj * 16 + l16 - H - DOUT;
                        atomicAdd(dst + col, leaky(acc[fi][fj][r] + bb[fj]));
                    }
                }
            }
    }
}

// ---------------------------------------------------------------------------
// f32 SGEMM for the node path (8% of FLOPs). 128x128 tile, KB=32, 8x8 micro.
// AM_PLAIN / AM_SCALED (row-scale by scale[m]); EP_STORE (f32) / EP_STORE16 (hi/lo f16).
// ---------------------------------------------------------------------------
template <int AMODE, int EPMODE, int K, int NTOT>
__global__ __launch_bounds__(256, 2) void sgemm_kernel(
    const float* __restrict__ A0, const float* __restrict__ scale,
    const float* __restrict__ W, const float* __restrict__ bias,
    float* __restrict__ C0, f16* __restrict__ C16h, f16* __restrict__ C16l,
    int M)
{
    constexpr int BM = 128, BN = 128, KB = 32;
    __shared__ float As[KB][BM + 4];
    __shared__ float Bs[KB][BN + 4];

    const int tid = threadIdx.x;
    const int tx = tid & 15;
    const int ty = tid >> 4;
    const int m0 = blockIdx.x * BM;
    const int n0 = blockIdx.y * BN;

    float acc[8][8];
#pragma unroll
    for (int i = 0; i < 8; ++i)
#pragma unroll
        for (int j = 0; j < 8; ++j) acc[i][j] = 0.0f;

    const int arow = tid >> 1;
    const int akb  = (tid & 1) * 16;
    int am = m0 + arow;
    if (am > M - 1) am = M - 1;
    const int bkr = tid >> 5;
    const int bn  = (tid & 31) * 4;
    float ascale = 1.0f;
    if (AMODE == AM_SCALED) ascale = scale[am];

#pragma unroll 1
    for (int k0 = 0; k0 < K; k0 += KB) {
        __syncthreads();
        const float* src = A0 + (size_t)am * K + k0;
#pragma unroll
        for (int q = 0; q < 4; ++q) {
            float4 v = *reinterpret_cast<const float4*>(src + akb + q * 4);
            if (AMODE == AM_SCALED) { v.x *= ascale; v.y *= ascale; v.z *= ascale; v.w *= ascale; }
            const int lk = akb + q * 4;
            As[lk + 0][arow] = v.x;
            As[lk + 1][arow] = v.y;
            As[lk + 2][arow] = v.z;
            As[lk + 3][arow] = v.w;
        }
#pragma unroll
        for (int q = 0; q < 4; ++q) {
            const int kr = bkr + q * 8;
            const float4 v = *reinterpret_cast<const float4*>(W + (size_t)(k0 + kr) * NTOT + n0 + bn);
            *reinterpret_cast<float4*>(&Bs[kr][bn]) = v;
        }
        __syncthreads();
#pragma unroll
        for (int kk = 0; kk < KB; ++kk) {
            float a[8], b[8];
            *reinterpret_cast<float4*>(&a[0]) = *reinterpret_cast<const float4*>(&As[kk][ty * 8]);
            *reinterpret_cast<float4*>(&a[4]) = *reinterpret_cast<const float4*>(&As[kk][ty * 8 + 4]);
            *reinterpret_cast<float4*>(&b[0]) = *reinterpret_cast<const float4*>(&Bs[kk][tx * 4]);
            *reinterpret_cast<float4*>(&b[4]) = *reinterpret_cast<const float4*>(&Bs[kk][64 + tx * 4]);
#pragma unroll
            for (int i = 0; i < 8; ++i)
#pragma unroll
                for (int j = 0; j < 8; ++j)
                    acc[i][j] = fmaf(a[i], b[j], acc[i][j]);
        }
    }

    float bv[8];
#pragma unroll
    for (int j = 0; j < 4; ++j) {
        bv[j]     = bias[n0 + tx * 4 + j];
        bv[4 + j] = bias[n0 + 64 + tx * 4 + j];
    }

#pragma unroll
    for (int i = 0; i < 8; ++i) {
        const int r = m0 + ty * 8 + i;
        if (r >= M) continue;
        if (EPMODE == EP_STORE) {
            float4 v0, v1;
            v0.x = leaky(acc[i][0] + bv[0]);
            v0.y = leaky(acc[i][1] + bv[1]);
            v0.z = leaky(acc[i][2] + bv[2]);
            v0.w = leaky(acc[i][3] + bv[3]);
            v1.x = leaky(acc[i][4] + bv[4]);
            v1.y = leaky(acc[i][5] + bv[5]);
            v1.z = leaky(acc[i][6] + bv[6]);
            v1.w = leaky(acc[i][7] + bv[7]);
            *reinterpret_cast<float4*>(&C0[(size_t)r * NTOT + n0 + tx * 4])      = v0;
            *reinterpret_cast<float4*>(&C0[(size_t)r * NTOT + n0 + 64 + tx * 4]) = v1;
        } else {
#pragma unroll
            for (int j = 0; j < 8; ++j) {
                const int col = n0 + (j < 4 ? tx * 4 + j : 64 + tx * 4 + (j - 4));
                f16 h, l;
                fsplit(leaky(acc[i][j] + bv[j]), h, l);
                C16h[(size_t)r * NTOT + col] = h;
                C16l[(size_t)r * NTOT + col] = l;
            }
        }
    }
}

// ---------------------------------------------------------------------------
// Final: out = leaky((obj_hi + obj_lo) @ W_bb + b_bb)
// ---------------------------------------------------------------------------
__global__ __launch_bounds__(256) void final_kernel(
    const f16* __restrict__ oh, const f16* __restrict__ ol,
    const float* __restrict__ W, const float* __restrict__ b, float* __restrict__ out)
{
    __shared__ float Ws[128 * 4];
    const int tid = threadIdx.x;
    for (int i = tid; i < 512; i += 256) Ws[i] = W[i];
    __syncthreads();
    const int r = blockIdx.x * 256 + tid;
    if (r >= NOBJ) return;
    float a0 = b[0], a1 = b[1], a2 = b[2], a3 = b[3];
    const f16* __restrict__ ph = oh + (size_t)r * 128;
    const f16* __restrict__ pl = ol + (size_t)r * 128;
#pragma unroll 4
    for (int k = 0; k < 128; k += 8) {
        const f16x8 hv = *reinterpret_cast<const f16x8*>(ph + k);
        const f16x8 lv = *reinterpret_cast<const f16x8*>(pl + k);
#pragma unroll
        for (int e = 0; e < 8; ++e) {
            const float x = (float)hv[e] + (float)lv[e];
            a0 = fmaf(x, Ws[(k + e) * 4 + 0], a0);
            a1 = fmaf(x, Ws[(k + e) * 4 + 1], a1);
            a2 = fmaf(x, Ws[(k + e) * 4 + 2], a2);
            a3 = fmaf(x, Ws[(k + e) * 4 + 3], a3);
        }
    }
    float4 o;
    o.x = leaky(a0);
    o.y = leaky(a1);
    o.z = leaky(a2);
    o.w = leaky(a3);
    *reinterpret_cast<float4*>(out + (size_t)r * 4) = o;
}

// ---------------------------------------------------------------------------
// Host orchestration — chunked, ws_size-adaptive (fixed ~266 MB + CH*2048 B).
// ---------------------------------------------------------------------------
extern "C" void kernel_launch(void* const* d_in, const int* in_sizes, int n_in,
                              void* d_out, int out_size, void* d_ws, size_t ws_size,
                              hipStream_t stream)
{
    const float* obj_vecs   = (const float*)d_in[0];
    const float* pred_vecs  = (const float*)d_in[1];
    const float* pred_boxes = (const float*)d_in[2];
    const int*   s_idx      = (const int*)d_in[3];
    const int*   o_idx      = (const int*)d_in[4];
    const float* W_emb      = (const float*)d_in[5];
    const float* b_emb      = (const float*)d_in[6];
    const float* W_bb       = (const float*)d_in[39];
    const float* b_bb       = (const float*)d_in[40];
    auto LP = [&](int layer, int which) -> const float* {
        return (const float*)d_in[7 + layer * 8 + which];
    };

    // ---- workspace carve ----
    uint8_t* p = (uint8_t*)d_ws;
    auto take = [&](size_t bytes) -> void* {
        void* r = (void*)p;
        p += (bytes + 255) & ~(size_t)255;
        return r;
    };
    f16*   predh  = (f16*)take((size_t)NTRI * 128 * 2);
    f16*   predl  = (f16*)take((size_t)NTRI * 128 * 2);
    float* pooled = (float*)take((size_t)NOBJ * 512 * 4);
    f16*   objh   = (f16*)take((size_t)NOBJ * 128 * 2);
    f16*   objl   = (f16*)take((size_t)NOBJ * 128 * 2);
    float* counts = (float*)take((size_t)NOBJ * 4);

    const int K1[4] = {192, 384, 384, 384};   // edge GEMM1: K = 3*DIN
    const int N1[4] = {512, 512, 512, 128};   // edge GEMM1: N = h
    const int K2[4] = {512, 512, 512, 128};   // edge GEMM2: K = h
    const int N2[4] = {1152, 1152, 1152, 384};// edge GEMM2: N = 2h+dout
    f16 *wah[4], *wal[4], *wbh[4], *wbl[4];
    for (int L = 0; L < 4; ++L) {
        wah[L] = (f16*)take((size_t)N1[L] * K1[L] * 2);
        wal[L] = (f16*)take((size_t)N1[L] * K1[L] * 2);
        wbh[L] = (f16*)take((size_t)N2[L] * K2[L] * 2);
        wbl[L] = (f16*)take((size_t)N2[L] * K2[L] * 2);
    }
    const size_t used = (size_t)(p - (uint8_t*)d_ws);
    const size_t rem = ws_size > used ? ws_size - used : 0;
    long long ch = (long long)(rem / 2048);   // edge: CH*512*2B*2 ; node: CH*512*4B
    ch = (ch / 128) * 128;
    if (ch > 50176) ch = 50176;
    if (ch < 128)   ch = 128;
    const int CH = (int)ch;
    f16*   hidh = (f16*)p;
    f16*   hidl = hidh + (size_t)CH * 512;
    float* scrF = (float*)p;                   // node hid (time-shared with hidh/hidl)

    const dim3 blk(256);

    // ---- prep: counts, embed, weight transpose/split ----
    hipMemsetAsync(counts, 0, NOBJ * sizeof(float), stream);
    embed_kernel<<<(NOBJ + 3) / 4, blk, 0, stream>>>(obj_vecs, pred_boxes, W_emb, b_emb, objh, objl);
    count_kernel<<<(NTRI + 255) / 256, blk, 0, stream>>>(s_idx, o_idx, counts);
    invcnt_kernel<<<(NOBJ + 255) / 256, blk, 0, stream>>>(counts);
    for (int L = 0; L < 4; ++L) {
        tsplit_kernel<<<dim3(N1[L] / 64, K1[L] / 64), blk, 0, stream>>>(LP(L, 0), K1[L], N1[L], wah[L], wal[L]);
        tsplit_kernel<<<dim3(N2[L] / 64, K2[L] / 64), blk, 0, stream>>>(LP(L, 2), K2[L], N2[L], wbh[L], wbl[L]);
    }

    // ---------------- layer 0: DIN=64, K1=192, H=512, DOUT=128 ----------------
    hipMemsetAsync(pooled, 0, (size_t)NOBJ * 512 * sizeof(float), stream);
    for (int r0 = 0; r0 < NTRI; r0 += CH) {
        const int CM = (NTRI - r0 < CH) ? (NTRI - r0) : CH;
        const int mt = (CM + 127) / 128;
        mgemm_kernel<AM_GATHER, EP_STORE, 64, 192, 512, 128, 512, 1><<<dim3(mt, 4), blk, 0, stream>>>(
            objh, objl, nullptr, nullptr, pred_vecs + (size_t)r0 * 64,
            s_idx + r0, o_idx + r0, wah[0], wal[0], LP(0, 1), nullptr, hidh, hidl, CM);
        mgemm_kernel<AM_PLAIN, EP_SPLIT, 0, 512, 512, 128, 1152, 0><<<dim3(mt, 9), blk, 0, stream>>>(
            hidh, hidl, nullptr, nullptr, nullptr,
            s_idx + r0, o_idx + r0, wbh[0], wbl[0], LP(0, 3), pooled,
            predh + (size_t)r0 * 128, predl + (size_t)r0 * 128, CM);
    }
    for (int r0 = 0; r0 < NOBJ; r0 += CH) {
        const int CM = (NOBJ - r0 < CH) ? (NOBJ - r0) : CH;
        const int mt = (CM + 127) / 128;
        sgemm_kernel<AM_SCALED, EP_STORE, 512, 512><<<dim3(mt, 4), blk, 0, stream>>>(
            pooled + (size_t)r0 * 512, counts + r0, LP(0, 4), LP(0, 5), scrF, nullptr, nullptr, CM);
        sgemm_kernel<AM_PLAIN, EP_STORE16, 512, 128><<<dim3(mt, 1), blk, 0, stream>>>(
            scrF, nullptr, LP(0, 6), LP(0, 7), nullptr, objh + (size_t)r0 * 128, objl + (size_t)r0 * 128, CM);
    }

    // ---------------- layers 1,2: DIN=128, K1=384, H=512, DOUT=128 ----------------
    for (int L = 1; L <= 2; ++L) {
        hipMemsetAsync(pooled, 0, (size_t)NOBJ * 512 * sizeof(float), stream);
        for (int r0 = 0; r0 < NTRI; r0 += CH) {
            const int CM = (NTRI - r0 < CH) ? (NTRI - r0) : CH;
            const int mt = (CM + 127) / 128;
            mgemm_kernel<AM_GATHER, EP_STORE, 128, 384, 512, 128, 512, 0><<<dim3(mt, 4), blk, 0, stream>>>(
                objh, objl, predh + (size_t)r0 * 128, predl + (size_t)r0 * 128, nullptr,
                s_idx + r0, o_idx + r0, wah[L], wal[L], LP(L, 1), nullptr, hidh, hidl, CM);
            mgemm_kernel<AM_PLAIN, EP_SPLIT, 0, 512, 512, 128, 1152, 0><<<dim3(mt, 9), blk, 0, stream>>>(
                hidh, hidl, nullptr, nullptr, nullptr,
                s_idx + r0, o_idx + r0, wbh[L], wbl[L], LP(L, 3), pooled,
                predh + (size_t)r0 * 128, predl + (size_t)r0 * 128, CM);
        }
        for (int r0 = 0; r0 < NOBJ; r0 += CH) {
            const int CM = (NOBJ - r0 < CH) ? (NOBJ - r0) : CH;
            const int mt = (CM + 127) / 128;
            sgemm_kernel<AM_SCALED, EP_STORE, 512, 512><<<dim3(mt, 4), blk, 0, stream>>>(
                pooled + (size_t)r0 * 512, counts + r0, LP(L, 4), LP(L, 5), scrF, nullptr, nullptr, CM);
            sgemm_kernel<AM_PLAIN, EP_STORE16, 512, 128><<<dim3(mt, 1), blk, 0, stream>>>(
                scrF, nullptr, LP(L, 6), LP(L, 7), nullptr, objh + (size_t)r0 * 128, objl + (size_t)r0 * 128, CM);
        }
    }

    // ---------------- layer 3: DIN=128, K1=384, H=128, DOUT=128 ----------------
    hipMemsetAsync(pooled, 0, (size_t)NOBJ * 128 * sizeof(float), stream);
    for (int r0 = 0; r0 < NTRI; r0 += CH) {
        const int CM = (NTRI - r0 < CH) ? (NTRI - r0) : CH;
        const int mt = (CM + 127) / 128;
        mgemm_kernel<AM_GATHER, EP_STORE, 128, 384, 128, 128, 128, 0><<<dim3(mt, 1), blk, 0, stream>>>(
            objh, objl, predh + (size_t)r0 * 128, predl + (size_t)r0 * 128, nullptr,
            s_idx + r0, o_idx + r0, wah[3], wal[3], LP(3, 1), nullptr, hidh, hidl, CM);
        mgemm_kernel<AM_PLAIN, EP_SPLIT, 0, 128, 128, 128, 384, 0><<<dim3(mt, 3), blk, 0, stream>>>(
            hidh, hidl, nullptr, nullptr, nullptr,
            s_idx + r0, o_idx + r0, wbh[3], wbl[3], LP(3, 3), pooled,
            predh + (size_t)r0 * 128, predl + (size_t)r0 * 128, CM);
    }
    for (int r0 = 0; r0 < NOBJ; r0 += CH) {
        const int CM = (NOBJ - r0 < CH) ? (NOBJ - r0) : CH;
        const int mt = (CM + 127) / 128;
        sgemm_kernel<AM_SCALED, EP_STORE, 128, 128><<<dim3(mt, 1), blk, 0, stream>>>(
            pooled + (size_t)r0 * 128, counts + r0, LP(3, 4), LP(3, 5), scrF, nullptr, nullptr, CM);
        sgemm_kernel<AM_PLAIN, EP_STORE16, 128, 128><<<dim3(mt, 1), blk, 0, stream>>>(
            scrF, nullptr, LP(3, 6), LP(3, 7), nullptr, objh + (size_t)r0 * 128, objl + (size_t)r0 * 128, CM);
    }

    // ---------------- final projection ----------------
    final_kernel<<<(NOBJ + 255) / 256, blk, 0, stream>>>(objh, objl, W_bb, b_bb, (float*)d_out);
}

// Round 4
// 50393.835 us; speedup vs baseline: 1.0795x; 1.0795x over previous
//
#include <hip/hip_runtime.h>
#include <cstddef>
#include <cstdint>

#define NOBJ 50000
#define NTRI 250000

typedef _Float16 f16;
typedef _Float16 f16x8 __attribute__((ext_vector_type(8)));
typedef float f32x4 __attribute__((ext_vector_type(4)));

__device__ __forceinline__ float leaky(float x) { return x > 0.0f ? x : 0.2f * x; }
__device__ __forceinline__ void fsplit(float y, f16& h, f16& l) {
    h = (f16)y;
    l = (f16)(y - (float)h);
}

// global -> LDS direct copy, 16B per lane. LDS dst must be wave-uniform;
// HW writes dst + lane*16. Global src is per-lane.
__device__ __forceinline__ void gl_lds16(const void* g, void* l) {
    __builtin_amdgcn_global_load_lds(
        (const __attribute__((address_space(1))) unsigned int*)g,
        (__attribute__((address_space(3))) unsigned int*)l, 16, 0, 0);
}

// ---------------------------------------------------------------------------
// Embedding: obj = leaky([obj_vecs | boxes] @ W_emb + b_emb) -> hi/lo f16
// ---------------------------------------------------------------------------
__global__ __launch_bounds__(256) void embed_kernel(
    const float* __restrict__ obj_vecs, const float* __restrict__ boxes,
    const float* __restrict__ W, const float* __restrict__ b,
    f16* __restrict__ oh, f16* __restrict__ ol)
{
    __shared__ float Ws[68 * 64];
    const int tid = threadIdx.x;
    for (int i = tid; i < 68 * 64; i += 256) Ws[i] = W[i];
    __syncthreads();
    const int row = blockIdx.x * 4 + (tid >> 6);
    const int col = tid & 63;
    if (row >= NOBJ) return;
    float acc = b[col];
    const float* __restrict__ a = obj_vecs + (size_t)row * 64;
#pragma unroll 16
    for (int k = 0; k < 64; ++k) acc = fmaf(a[k], Ws[k * 64 + col], acc);
    const float* __restrict__ bx = boxes + (size_t)row * 4;
#pragma unroll
    for (int k = 0; k < 4; ++k) acc = fmaf(bx[k], Ws[(64 + k) * 64 + col], acc);
    f16 h, l;
    fsplit(leaky(acc), h, l);
    oh[(size_t)row * 64 + col] = h;
    ol[(size_t)row * 64 + col] = l;
}

// ---------------------------------------------------------------------------
// Weight transpose + split: W[K][N] f32 -> Th/Tl[N][K] f16
// ---------------------------------------------------------------------------
__global__ __launch_bounds__(256) void tsplit_kernel(
    const float* __restrict__ W, int K, int N,
    f16* __restrict__ Th, f16* __restrict__ Tl)
{
    __shared__ float T[64][65];
    const int n0 = blockIdx.x * 64, k0 = blockIdx.y * 64;
    const int tc = threadIdx.x & 63, tr = threadIdx.x >> 6;
    for (int r = tr; r < 64; r += 4) {
        const int k = k0 + r, n = n0 + tc;
        T[r][tc] = (k < K && n < N) ? W[(size_t)k * N + n] : 0.0f;
    }
    __syncthreads();
    for (int r = tr; r < 64; r += 4) {
        const int n = n0 + r, k = k0 + tc;
        if (n < N && k < K) {
            f16 h, l;
            fsplit(T[tc][r], h, l);
            Th[(size_t)n * K + k] = h;
            Tl[(size_t)n * K + k] = l;
        }
    }
}

__global__ __launch_bounds__(256) void count_kernel(
    const int* __restrict__ s, const int* __restrict__ o, float* __restrict__ cnt)
{
    const int t = blockIdx.x * 256 + threadIdx.x;
    if (t < NTRI) {
        atomicAdd(&cnt[s[t]], 1.0f);
        atomicAdd(&cnt[o[t]], 1.0f);
    }
}

__global__ __launch_bounds__(256) void invcnt_kernel(float* __restrict__ cnt)
{
    const int i = blockIdx.x * 256 + threadIdx.x;
    if (i < NOBJ) cnt[i] = 1.0f / fmaxf(cnt[i], 1.0f);
}

enum { AM_PLAIN = 0, AM_GATHER = 1, AM_SCALED = 2 };
enum { EP_STORE = 0, EP_SPLIT = 1, EP_STORE16 = 2 };

// ---------------------------------------------------------------------------
// Split-f16 MFMA GEMM, global_load_lds staging, linear LDS [128][32] f16.
// 128x128 tile, K-step 32, 4 waves (2x2 of 64x64), 3 MFMA passes per frag
// (hi*hi + hi*lo + lo*hi). Frag & C/D layouts identical to the HW-verified
// round-3 kernel; only the staging mechanics changed.
// Staging map: instr p in {0,1}; wave w covers LDS rows [p*64 + w*16, +16);
// lane l -> row = p*64 + w*16 + (l>>2), 16B chunk = l&3. LDS dst uniform.
// ---------------------------------------------------------------------------
template <int AMODE, int EPMODE, int DIN, int K, int H, int DOUT, int NTOT, int PRED32>
__global__ __launch_bounds__(256, 2) void mgemm_kernel(
    const f16* __restrict__ A0h, const f16* __restrict__ A0l,   // obj (gather) or hid (plain)
    const f16* __restrict__ A1h, const f16* __restrict__ A1l,   // pred f16 (layers>=1)
    const float* __restrict__ A1f,                              // pred f32 (layer0)
    const int* __restrict__ sidx, const int* __restrict__ oidx,
    const f16* __restrict__ Bth, const f16* __restrict__ Btl,   // Wt [NTOT][K]
    const float* __restrict__ bias,
    float* __restrict__ C0,                                     // EP_SPLIT: pooled f32
    f16* __restrict__ D0h, f16* __restrict__ D0l,               // EP_STORE: hid ; EP_SPLIT: pred
    int M)
{
    __shared__ f16 Ah[128][32], Al[128][32], Bh[128][32], Bl[128][32];
    __shared__ int sIdxL[128], oIdxL[128];

    const int tid = threadIdx.x;
    const int wave = tid >> 6, lane = tid & 63;
    const int l16 = lane & 15, lq = lane >> 4;
    const int m0 = blockIdx.x * 128, n0 = blockIdx.y * 128;
    const int wr = (wave >> 1) * 64, wc = (wave & 1) * 64;

    if (AMODE == AM_GATHER) {
        if (tid < 128) {
            int rr = m0 + tid;
            if (rr > M - 1) rr = M - 1;
            sIdxL[tid] = sidx[rr];
            oIdxL[tid] = oidx[rr];
        }
        __syncthreads();
    }

    // per-thread staging rows (fixed across K-steps)
    const int rA0 = wave * 16 + (lane >> 2);        // p=0: rows 0..63
    const int rA1 = 64 + wave * 16 + (lane >> 2);   // p=1: rows 64..127
    const int cc  = (lane & 3) * 8;                 // f16 offset of this lane's 16B chunk
    int gA0 = m0 + rA0; if (gA0 > M - 1) gA0 = M - 1;
    int gA1 = m0 + rA1; if (gA1 > M - 1) gA1 = M - 1;

    // source pointers per region
    const f16 *aSh0 = nullptr, *aSl0 = nullptr, *aSh1 = nullptr, *aSl1 = nullptr;
    const f16 *aPh0 = nullptr, *aPl0 = nullptr, *aPh1 = nullptr, *aPl1 = nullptr;
    const f16 *aOh0 = nullptr, *aOl0 = nullptr, *aOh1 = nullptr, *aOl1 = nullptr;
    const float* pf = nullptr;
    if (AMODE == AM_GATHER) {
        const int s0 = sIdxL[rA0], s1 = sIdxL[rA1];
        const int o0 = oIdxL[rA0], o1 = oIdxL[rA1];
        aSh0 = A0h + (size_t)s0 * DIN + cc;  aSl0 = A0l + (size_t)s0 * DIN + cc;
        aSh1 = A0h + (size_t)s1 * DIN + cc;  aSl1 = A0l + (size_t)s1 * DIN + cc;
        aOh0 = A0h + (size_t)o0 * DIN + cc;  aOl0 = A0l + (size_t)o0 * DIN + cc;
        aOh1 = A0h + (size_t)o1 * DIN + cc;  aOl1 = A0l + (size_t)o1 * DIN + cc;
        if (PRED32) {
            int gw = m0 + (tid >> 1);
            if (gw > M - 1) gw = M - 1;
            pf = A1f + (size_t)gw * DIN + (tid & 1) * 16;
        } else {
            aPh0 = A1h + (size_t)gA0 * DIN + cc;  aPl0 = A1l + (size_t)gA0 * DIN + cc;
            aPh1 = A1h + (size_t)gA1 * DIN + cc;  aPl1 = A1l + (size_t)gA1 * DIN + cc;
        }
    } else {
        aSh0 = A0h + (size_t)gA0 * K + cc;  aSl0 = A0l + (size_t)gA0 * K + cc;
        aSh1 = A0h + (size_t)gA1 * K + cc;  aSl1 = A0l + (size_t)gA1 * K + cc;
    }
    const f16* bH0 = Bth + (size_t)(n0 + rA0) * K + cc;
    const f16* bH1 = Bth + (size_t)(n0 + rA1) * K + cc;
    const f16* bL0 = Btl + (size_t)(n0 + rA0) * K + cc;
    const f16* bL1 = Btl + (size_t)(n0 + rA1) * K + cc;

    f32x4 acc[4][4];
    const f32x4 zz = {0.0f, 0.0f, 0.0f, 0.0f};
#pragma unroll
    for (int i = 0; i < 4; ++i)
#pragma unroll
        for (int j = 0; j < 4; ++j) acc[i][j] = zz;

#pragma unroll 1
    for (int k0 = 0; k0 < K; k0 += 32) {
        // ---- stage A ----
        if (PRED32 && AMODE == AM_GATHER && k0 >= DIN && k0 < 2 * DIN) {
            // f32 pred region: reg-convert + ds_write (layer 0 only)
            const int arowW = tid >> 1;
            const int koffW = (tid & 1) * 16;
            const float* src = pf + (k0 - DIN);
            float v[16];
#pragma unroll
            for (int q = 0; q < 4; ++q)
                *reinterpret_cast<float4*>(&v[q * 4]) = *reinterpret_cast<const float4*>(src + q * 4);
            f16 hh[16], ll[16];
#pragma unroll
            for (int e = 0; e < 16; ++e) fsplit(v[e], hh[e], ll[e]);
            *reinterpret_cast<f16x8*>(&Ah[arowW][koffW])     = *reinterpret_cast<f16x8*>(&hh[0]);
            *reinterpret_cast<f16x8*>(&Ah[arowW][koffW + 8]) = *reinterpret_cast<f16x8*>(&hh[8]);
            *reinterpret_cast<f16x8*>(&Al[arowW][koffW])     = *reinterpret_cast<f16x8*>(&ll[0]);
            *reinterpret_cast<f16x8*>(&Al[arowW][koffW + 8]) = *reinterpret_cast<f16x8*>(&ll[8]);
        } else {
            const f16 *sh0, *sl0, *sh1, *sl1;
            int off;
            if (AMODE != AM_GATHER) {
                sh0 = aSh0; sl0 = aSl0; sh1 = aSh1; sl1 = aSl1; off = k0;
            } else if (k0 < DIN) {
                sh0 = aSh0; sl0 = aSl0; sh1 = aSh1; sl1 = aSl1; off = k0;
            } else if (k0 < 2 * DIN) {
                sh0 = aPh0; sl0 = aPl0; sh1 = aPh1; sl1 = aPl1; off = k0 - DIN;
            } else {
                sh0 = aOh0; sl0 = aOl0; sh1 = aOh1; sl1 = aOl1; off = k0 - 2 * DIN;
            }
            gl_lds16(sh0 + off, &Ah[wave * 16][0]);
            gl_lds16(sh1 + off, &Ah[64 + wave * 16][0]);
            gl_lds16(sl0 + off, &Al[wave * 16][0]);
            gl_lds16(sl1 + off, &Al[64 + wave * 16][0]);
        }
        // ---- stage B ----
        gl_lds16(bH0 + k0, &Bh[wave * 16][0]);
        gl_lds16(bH1 + k0, &Bh[64 + wave * 16][0]);
        gl_lds16(bL0 + k0, &Bl[wave * 16][0]);
        gl_lds16(bL1 + k0, &Bl[64 + wave * 16][0]);
        __syncthreads();   // drains vmcnt (gload) + lgkmcnt (ds_write) then barriers
        // ---- fragments + MFMA ----
        f16x8 fah[4], fal[4], fbh[4], fbl[4];
#pragma unroll
        for (int fi = 0; fi < 4; ++fi) {
            const int r = wr + fi * 16 + l16;
            fah[fi] = *reinterpret_cast<const f16x8*>(&Ah[r][lq * 8]);
            fal[fi] = *reinterpret_cast<const f16x8*>(&Al[r][lq * 8]);
        }
#pragma unroll
        for (int fj = 0; fj < 4; ++fj) {
            const int c = wc + fj * 16 + l16;
            fbh[fj] = *reinterpret_cast<const f16x8*>(&Bh[c][lq * 8]);
            fbl[fj] = *reinterpret_cast<const f16x8*>(&Bl[c][lq * 8]);
        }
#pragma unroll
        for (int fi = 0; fi < 4; ++fi)
#pragma unroll
            for (int fj = 0; fj < 4; ++fj) {
                acc[fi][fj] = __builtin_amdgcn_mfma_f32_16x16x32_f16(fah[fi], fbh[fj], acc[fi][fj], 0, 0, 0);
                acc[fi][fj] = __builtin_amdgcn_mfma_f32_16x16x32_f16(fah[fi], fbl[fj], acc[fi][fj], 0, 0, 0);
                acc[fi][fj] = __builtin_amdgcn_mfma_f32_16x16x32_f16(fal[fi], fbh[fj], acc[fi][fj], 0, 0, 0);
            }
        __syncthreads();   // protect LDS from next stage
    }

    // ---- epilogue (identical to round-3, HW-verified) ----
    float bb[4];
#pragma unroll
    for (int fj = 0; fj < 4; ++fj) bb[fj] = bias[n0 + wc + fj * 16 + l16];

    if (EPMODE == EP_STORE) {
#pragma unroll
        for (int fi = 0; fi < 4; ++fi)
#pragma unroll
            for (int r = 0; r < 4; ++r) {
                const int rowg = m0 + wr + fi * 16 + lq * 4 + r;
                if (rowg >= M) continue;
#pragma unroll
                for (int fj = 0; fj < 4; ++fj) {
                    const int col = n0 + wc + fj * 16 + l16;
                    f16 h, l;
                    fsplit(leaky(acc[fi][fj][r] + bb[fj]), h, l);
                    D0h[(size_t)rowg * NTOT + col] = h;
                    D0l[(size_t)rowg * NTOT + col] = l;
                }
            }
    } else {
        constexpr int SCH = H / 128;
        const int chunk = blockIdx.y;
#pragma unroll
        for (int fi = 0; fi < 4; ++fi)
#pragma unroll
            for (int r = 0; r < 4; ++r) {
                const int rowg = m0 + wr + fi * 16 + lq * 4 + r;
                if (rowg >= M) continue;
                if (chunk < SCH) {
                    const int t = sidx[rowg];
                    float* dst = C0 + (size_t)t * H;
#pragma unroll
                    for (int fj = 0; fj < 4; ++fj) {
                        const int col = n0 + wc + fj * 16 + l16;
                        atomicAdd(dst + col, leaky(acc[fi][fj][r] + bb[fj]));
                    }
                } else if (chunk == SCH) {
#pragma unroll
                    for (int fj = 0; fj < 4; ++fj) {
                        const int col = n0 + wc + fj * 16 + l16 - H;
                        f16 h, l;
                        fsplit(leaky(acc[fi][fj][r] + bb[fj]), h, l);
                        D0h[(size_t)rowg * DOUT + col] = h;
                        D0l[(size_t)rowg * DOUT + col] = l;
                    }
                } else {
                    const int t = oidx[rowg];
                    float* dst = C0 + (size_t)t * H;
#pragma unroll
                    for (int fj = 0; fj < 4; ++fj) {
                        const int col = n0 + wc + fj * 16 + l16 - H - DOUT;
                        atomicAdd(dst + col, leaky(acc[fi][fj][r] + bb[fj]));
                    }
                }
            }
    }
}

// ---------------------------------------------------------------------------
// f32 SGEMM for the node path (8% of FLOPs) — unchanged from round 3.
// ---------------------------------------------------------------------------
template <int AMODE, int EPMODE, int K, int NTOT>
__global__ __launch_bounds__(256, 2) void sgemm_kernel(
    const float* __restrict__ A0, const float* __restrict__ scale,
    const float* __restrict__ W, const float* __restrict__ bias,
    float* __restrict__ C0, f16* __restrict__ C16h, f16* __restrict__ C16l,
    int M)
{
    constexpr int BM = 128, BN = 128, KB = 32;
    __shared__ float As[KB][BM + 4];
    __shared__ float Bs[KB][BN + 4];

    const int tid = threadIdx.x;
    const int tx = tid & 15;
    const int ty = tid >> 4;
    const int m0 = blockIdx.x * BM;
    const int n0 = blockIdx.y * BN;

    float acc[8][8];
#pragma unroll
    for (int i = 0; i < 8; ++i)
#pragma unroll
        for (int j = 0; j < 8; ++j) acc[i][j] = 0.0f;

    const int arow = tid >> 1;
    const int akb  = (tid & 1) * 16;
    int am = m0 + arow;
    if (am > M - 1) am = M - 1;
    const int bkr = tid >> 5;
    const int bn  = (tid & 31) * 4;
    float ascale = 1.0f;
    if (AMODE == AM_SCALED) ascale = scale[am];

#pragma unroll 1
    for (int k0 = 0; k0 < K; k0 += KB) {
        __syncthreads();
        const float* src = A0 + (size_t)am * K + k0;
#pragma unroll
        for (int q = 0; q < 4; ++q) {
            float4 v = *reinterpret_cast<const float4*>(src + akb + q * 4);
            if (AMODE == AM_SCALED) { v.x *= ascale; v.y *= ascale; v.z *= ascale; v.w *= ascale; }
            const int lk = akb + q * 4;
            As[lk + 0][arow] = v.x;
            As[lk + 1][arow] = v.y;
            As[lk + 2][arow] = v.z;
            As[lk + 3][arow] = v.w;
        }
#pragma unroll
        for (int q = 0; q < 4; ++q) {
            const int kr = bkr + q * 8;
            const float4 v = *reinterpret_cast<const float4*>(W + (size_t)(k0 + kr) * NTOT + n0 + bn);
            *reinterpret_cast<float4*>(&Bs[kr][bn]) = v;
        }
        __syncthreads();
#pragma unroll
        for (int kk = 0; kk < KB; ++kk) {
            float a[8], b[8];
            *reinterpret_cast<float4*>(&a[0]) = *reinterpret_cast<const float4*>(&As[kk][ty * 8]);
            *reinterpret_cast<float4*>(&a[4]) = *reinterpret_cast<const float4*>(&As[kk][ty * 8 + 4]);
            *reinterpret_cast<float4*>(&b[0]) = *reinterpret_cast<const float4*>(&Bs[kk][tx * 4]);
            *reinterpret_cast<float4*>(&b[4]) = *reinterpret_cast<const float4*>(&Bs[kk][64 + tx * 4]);
#pragma unroll
            for (int i = 0; i < 8; ++i)
#pragma unroll
                for (int j = 0; j < 8; ++j)
                    acc[i][j] = fmaf(a[i], b[j], acc[i][j]);
        }
    }

    float bv[8];
#pragma unroll
    for (int j = 0; j < 4; ++j) {
        bv[j]     = bias[n0 + tx * 4 + j];
        bv[4 + j] = bias[n0 + 64 + tx * 4 + j];
    }

#pragma unroll
    for (int i = 0; i < 8; ++i) {
        const int r = m0 + ty * 8 + i;
        if (r >= M) continue;
        if (EPMODE == EP_STORE) {
            float4 v0, v1;
            v0.x = leaky(acc[i][0] + bv[0]);
            v0.y = leaky(acc[i][1] + bv[1]);
            v0.z = leaky(acc[i][2] + bv[2]);
            v0.w = leaky(acc[i][3] + bv[3]);
            v1.x = leaky(acc[i][4] + bv[4]);
            v1.y = leaky(acc[i][5] + bv[5]);
            v1.z = leaky(acc[i][6] + bv[6]);
            v1.w = leaky(acc[i][7] + bv[7]);
            *reinterpret_cast<float4*>(&C0[(size_t)r * NTOT + n0 + tx * 4])      = v0;
            *reinterpret_cast<float4*>(&C0[(size_t)r * NTOT + n0 + 64 + tx * 4]) = v1;
        } else {
#pragma unroll
            for (int j = 0; j < 8; ++j) {
                const int col = n0 + (j < 4 ? tx * 4 + j : 64 + tx * 4 + (j - 4));
                f16 h, l;
                fsplit(leaky(acc[i][j] + bv[j]), h, l);
                C16h[(size_t)r * NTOT + col] = h;
                C16l[(size_t)r * NTOT + col] = l;
            }
        }
    }
}

// ---------------------------------------------------------------------------
// Final: out = leaky((obj_hi + obj_lo) @ W_bb + b_bb)
// ---------------------------------------------------------------------------
__global__ __launch_bounds__(256) void final_kernel(
    const f16* __restrict__ oh, const f16* __restrict__ ol,
    const float* __restrict__ W, const float* __restrict__ b, float* __restrict__ out)
{
    __shared__ float Ws[128 * 4];
    const int tid = threadIdx.x;
    for (int i = tid; i < 512; i += 256) Ws[i] = W[i];
    __syncthreads();
    const int r = blockIdx.x * 256 + tid;
    if (r >= NOBJ) return;
    float a0 = b[0], a1 = b[1], a2 = b[2], a3 = b[3];
    const f16* __restrict__ ph = oh + (size_t)r * 128;
    const f16* __restrict__ pl = ol + (size_t)r * 128;
#pragma unroll 4
    for (int k = 0; k < 128; k += 8) {
        const f16x8 hv = *reinterpret_cast<const f16x8*>(ph + k);
        const f16x8 lv = *reinterpret_cast<const f16x8*>(pl + k);
#pragma unroll
        for (int e = 0; e < 8; ++e) {
            const float x = (float)hv[e] + (float)lv[e];
            a0 = fmaf(x, Ws[(k + e) * 4 + 0], a0);
            a1 = fmaf(x, Ws[(k + e) * 4 + 1], a1);
            a2 = fmaf(x, Ws[(k + e) * 4 + 2], a2);
            a3 = fmaf(x, Ws[(k + e) * 4 + 3], a3);
        }
    }
    float4 o;
    o.x = leaky(a0);
    o.y = leaky(a1);
    o.z = leaky(a2);
    o.w = leaky(a3);
    *reinterpret_cast<float4*>(out + (size_t)r * 4) = o;
}

// ---------------------------------------------------------------------------
// Host orchestration — identical structure to round 3 (passed).
// ---------------------------------------------------------------------------
extern "C" void kernel_launch(void* const* d_in, const int* in_sizes, int n_in,
                              void* d_out, int out_size, void* d_ws, size_t ws_size,
                              hipStream_t stream)
{
    const float* obj_vecs   = (const float*)d_in[0];
    const float* pred_vecs  = (const float*)d_in[1];
    const float* pred_boxes = (const float*)d_in[2];
    const int*   s_idx      = (const int*)d_in[3];
    const int*   o_idx      = (const int*)d_in[4];
    const float* W_emb      = (const float*)d_in[5];
    const float* b_emb      = (const float*)d_in[6];
    const float* W_bb       = (const float*)d_in[39];
    const float* b_bb       = (const float*)d_in[40];
    auto LP = [&](int layer, int which) -> const float* {
        return (const float*)d_in[7 + layer * 8 + which];
    };

    uint8_t* p = (uint8_t*)d_ws;
    auto take = [&](size_t bytes) -> void* {
        void* r = (void*)p;
        p += (bytes + 255) & ~(size_t)255;
        return r;
    };
    f16*   predh  = (f16*)take((size_t)NTRI * 128 * 2);
    f16*   predl  = (f16*)take((size_t)NTRI * 128 * 2);
    float* pooled = (float*)take((size_t)NOBJ * 512 * 4);
    f16*   objh   = (f16*)take((size_t)NOBJ * 128 * 2);
    f16*   objl   = (f16*)take((size_t)NOBJ * 128 * 2);
    float* counts = (float*)take((size_t)NOBJ * 4);

    const int K1[4] = {192, 384, 384, 384};
    const int N1[4] = {512, 512, 512, 128};
    const int K2[4] = {512, 512, 512, 128};
    const int N2[4] = {1152, 1152, 1152, 384};
    f16 *wah[4], *wal[4], *wbh[4], *wbl[4];
    for (int L = 0; L < 4; ++L) {
        wah[L] = (f16*)take((size_t)N1[L] * K1[L] * 2);
        wal[L] = (f16*)take((size_t)N1[L] * K1[L] * 2);
        wbh[L] = (f16*)take((size_t)N2[L] * K2[L] * 2);
        wbl[L] = (f16*)take((size_t)N2[L] * K2[L] * 2);
    }
    const size_t used = (size_t)(p - (uint8_t*)d_ws);
    const size_t rem = ws_size > used ? ws_size - used : 0;
    long long ch = (long long)(rem / 2048);
    ch = (ch / 128) * 128;
    if (ch > 50176) ch = 50176;
    if (ch < 128)   ch = 128;
    const int CH = (int)ch;
    f16*   hidh = (f16*)p;
    f16*   hidl = hidh + (size_t)CH * 512;
    float* scrF = (float*)p;

    const dim3 blk(256);

    hipMemsetAsync(counts, 0, NOBJ * sizeof(float), stream);
    embed_kernel<<<(NOBJ + 3) / 4, blk, 0, stream>>>(obj_vecs, pred_boxes, W_emb, b_emb, objh, objl);
    count_kernel<<<(NTRI + 255) / 256, blk, 0, stream>>>(s_idx, o_idx, counts);
    invcnt_kernel<<<(NOBJ + 255) / 256, blk, 0, stream>>>(counts);
    for (int L = 0; L < 4; ++L) {
        tsplit_kernel<<<dim3(N1[L] / 64, K1[L] / 64), blk, 0, stream>>>(LP(L, 0), K1[L], N1[L], wah[L], wal[L]);
        tsplit_kernel<<<dim3(N2[L] / 64, K2[L] / 64), blk, 0, stream>>>(LP(L, 2), K2[L], N2[L], wbh[L], wbl[L]);
    }

    // ---------------- layer 0: DIN=64, K1=192, H=512, DOUT=128 ----------------
    hipMemsetAsync(pooled, 0, (size_t)NOBJ * 512 * sizeof(float), stream);
    for (int r0 = 0; r0 < NTRI; r0 += CH) {
        const int CM = (NTRI - r0 < CH) ? (NTRI - r0) : CH;
        const int mt = (CM + 127) / 128;
        mgemm_kernel<AM_GATHER, EP_STORE, 64, 192, 512, 128, 512, 1><<<dim3(mt, 4), blk, 0, stream>>>(
            objh, objl, nullptr, nullptr, pred_vecs + (size_t)r0 * 64,
            s_idx + r0, o_idx + r0, wah[0], wal[0], LP(0, 1), nullptr, hidh, hidl, CM);
        mgemm_kernel<AM_PLAIN, EP_SPLIT, 0, 512, 512, 128, 1152, 0><<<dim3(mt, 9), blk, 0, stream>>>(
            hidh, hidl, nullptr, nullptr, nullptr,
            s_idx + r0, o_idx + r0, wbh[0], wbl[0], LP(0, 3), pooled,
            predh + (size_t)r0 * 128, predl + (size_t)r0 * 128, CM);
    }
    for (int r0 = 0; r0 < NOBJ; r0 += CH) {
        const int CM = (NOBJ - r0 < CH) ? (NOBJ - r0) : CH;
        const int mt = (CM + 127) / 128;
        sgemm_kernel<AM_SCALED, EP_STORE, 512, 512><<<dim3(mt, 4), blk, 0, stream>>>(
            pooled + (size_t)r0 * 512, counts + r0, LP(0, 4), LP(0, 5), scrF, nullptr, nullptr, CM);
        sgemm_kernel<AM_PLAIN, EP_STORE16, 512, 128><<<dim3(mt, 1), blk, 0, stream>>>(
            scrF, nullptr, LP(0, 6), LP(0, 7), nullptr, objh + (size_t)r0 * 128, objl + (size_t)r0 * 128, CM);
    }

    // ---------------- layers 1,2: DIN=128, K1=384, H=512, DOUT=128 ----------------
    for (int L = 1; L <= 2; ++L) {
        hipMemsetAsync(pooled, 0, (size_t)NOBJ * 512 * sizeof(float), stream);
        for (int r0 = 0; r0 < NTRI; r0 += CH) {
            const int CM = (NTRI - r0 < CH) ? (NTRI - r0) : CH;
            const int mt = (CM + 127) / 128;
            mgemm_kernel<AM_GATHER, EP_STORE, 128, 384, 512, 128, 512, 0><<<dim3(mt, 4), blk, 0, stream>>>(
                objh, objl, predh + (size_t)r0 * 128, predl + (size_t)r0 * 128, nullptr,
                s_idx + r0, o_idx + r0, wah[L], wal[L], LP(L, 1), nullptr, hidh, hidl, CM);
            mgemm_kernel<AM_PLAIN, EP_SPLIT, 0, 512, 512, 128, 1152, 0><<<dim3(mt, 9), blk, 0, stream>>>(
                hidh, hidl, nullptr, nullptr, nullptr,
                s_idx + r0, o_idx + r0, wbh[L], wbl[L], LP(L, 3), pooled,
                predh + (size_t)r0 * 128, predl + (size_t)r0 * 128, CM);
        }
        for (int r0 = 0; r0 < NOBJ; r0 += CH) {
            const int CM = (NOBJ - r0 < CH) ? (NOBJ - r0) : CH;
            const int mt = (CM + 127) / 128;
            sgemm_kernel<AM_SCALED, EP_STORE, 512, 512><<<dim3(mt, 4), blk, 0, stream>>>(
                pooled + (size_t)r0 * 512, counts + r0, LP(L, 4), LP(L, 5), scrF, nullptr, nullptr, CM);
            sgemm_kernel<AM_PLAIN, EP_STORE16, 512, 128><<<dim3(mt, 1), blk, 0, stream>>>(
                scrF, nullptr, LP(L, 6), LP(L, 7), nullptr, objh + (size_t)r0 * 128, objl + (size_t)r0 * 128, CM);
        }
    }

    // ---------------- layer 3: DIN=128, K1=384, H=128, DOUT=128 ----------------
    hipMemsetAsync(pooled, 0, (size_t)NOBJ * 128 * sizeof(float), stream);
    for (int r0 = 0; r0 < NTRI; r0 += CH) {
        const int CM = (NTRI - r0 < CH) ? (NTRI - r0) : CH;
        const int mt = (CM + 127) / 128;
        mgemm_kernel<AM_GATHER, EP_STORE, 128, 384, 128, 128, 128, 0><<<dim3(mt, 1), blk, 0, stream>>>(
            objh, objl, predh + (size_t)r0 * 128, predl + (size_t)r0 * 128, nullptr,
            s_idx + r0, o_idx + r0, wah[3], wal[3], LP(3, 1), nullptr, hidh, hidl, CM);
        mgemm_kernel<AM_PLAIN, EP_SPLIT, 0, 128, 128, 128, 384, 0><<<dim3(mt, 3), blk, 0, stream>>>(
            hidh, hidl, nullptr, nullptr, nullptr,
            s_idx + r0, o_idx + r0, wbh[3], wbl[3], LP(3, 3), pooled,
            predh + (size_t)r0 * 128, predl + (size_t)r0 * 128, CM);
    }
    for (int r0 = 0; r0 < NOBJ; r0 += CH) {
        const int CM = (NOBJ - r0 < CH) ? (NOBJ - r0) : CH;
        const int mt = (CM + 127) / 128;
        sgemm_kernel<AM_SCALED, EP_STORE, 128, 128><<<dim3(mt, 1), blk, 0, stream>>>(
            pooled + (size_t)r0 * 128, counts + r0, LP(3, 4), LP(3, 5), scrF, nullptr, nullptr, CM);
        sgemm_kernel<AM_PLAIN, EP_STORE16, 128, 128><<<dim3(mt, 1), blk, 0, stream>>>(
            scrF, nullptr, LP(3, 6), LP(3, 7), nullptr, objh + (size_t)r0 * 128, objl + (size_t)r0 * 128, CM);
    }

    final_kernel<<<(NOBJ + 255) / 256, blk, 0, stream>>>(objh, objl, W_bb, b_bb, (float*)d_out);
}

// Round 8
// 9079.475 us; speedup vs baseline: 5.9916x; 5.5503x over previous
//
#include <hip/hip_runtime.h>
#include <cstddef>
#include <cstdint>

#define NOBJ 50000
#define NTRI 250000

typedef _Float16 f16;
typedef _Float16 f16x8 __attribute__((ext_vector_type(8)));
typedef float f32x4 __attribute__((ext_vector_type(4)));

__device__ __forceinline__ float leaky(float x) { return x > 0.0f ? x : 0.2f * x; }
__device__ __forceinline__ void fsplit(float y, f16& h, f16& l) {
    h = (f16)y;
    l = (f16)(y - (float)h);
}
// e5m2 is f16 truncated to the top byte (same exponent field). RNE on bit 8.
__device__ __forceinline__ uint8_t f16_to_e5m2(f16 x) {
    const uint16_t b = __builtin_bit_cast(unsigned short, x);
    const uint16_t r = (uint16_t)(b + 0x7F + ((b >> 8) & 1));
    return (uint8_t)(r >> 8);
}
// 8 e5m2 bytes (two u32 words) -> f16x8 via byte<<8
__device__ __forceinline__ f16x8 e5m2x8_to_f16x8(uint32_t w0, uint32_t w1) {
    union { uint32_t u[4]; f16x8 v; } r;
    r.u[0] = ((w0 << 8) & 0xFF00u) | ((w0 << 16) & 0xFF000000u);
    r.u[1] = ((w0 >> 8) & 0xFF00u) | ( w0        & 0xFF000000u);
    r.u[2] = ((w1 << 8) & 0xFF00u) | ((w1 << 16) & 0xFF000000u);
    r.u[3] = ((w1 >> 8) & 0xFF00u) | ( w1        & 0xFF000000u);
    return r.v;
}

// global -> LDS direct copy, 16B per lane. LDS dst wave-uniform; HW writes dst + lane*16.
__device__ __forceinline__ void gl_lds16(const void* g, void* l) {
    __builtin_amdgcn_global_load_lds(
        (const __attribute__((address_space(1))) unsigned int*)g,
        (__attribute__((address_space(3))) unsigned int*)l, 16, 0, 0);
}

// ---------------------------------------------------------------------------
// Embedding: obj = leaky([obj_vecs | boxes] @ W_emb + b_emb) -> hi/lo f16
// ---------------------------------------------------------------------------
__global__ __launch_bounds__(256) void embed_kernel(
    const float* __restrict__ obj_vecs, const float* __restrict__ boxes,
    const float* __restrict__ W, const float* __restrict__ b,
    f16* __restrict__ oh, f16* __restrict__ ol)
{
    __shared__ float Ws[68 * 64];
    const int tid = threadIdx.x;
    for (int i = tid; i < 68 * 64; i += 256) Ws[i] = W[i];
    __syncthreads();
    const int row = blockIdx.x * 4 + (tid >> 6);
    const int col = tid & 63;
    if (row >= NOBJ) return;
    float acc = b[col];
    const float* __restrict__ a = obj_vecs + (size_t)row * 64;
#pragma unroll 16
    for (int k = 0; k < 64; ++k) acc = fmaf(a[k], Ws[k * 64 + col], acc);
    const float* __restrict__ bx = boxes + (size_t)row * 4;
#pragma unroll
    for (int k = 0; k < 4; ++k) acc = fmaf(bx[k], Ws[(64 + k) * 64 + col], acc);
    f16 h, l;
    fsplit(leaky(acc), h, l);
    oh[(size_t)row * 64 + col] = h;
    ol[(size_t)row * 64 + col] = l;
}

// ---------------------------------------------------------------------------
// Weight transpose + split: W[K][N] f32 -> Th/Tl[N][K] f16
// ---------------------------------------------------------------------------
__global__ __launch_bounds__(256) void tsplit_kernel(
    const float* __restrict__ W, int K, int N,
    f16* __restrict__ Th, f16* __restrict__ Tl)
{
    __shared__ float T[64][65];
    const int n0 = blockIdx.x * 64, k0 = blockIdx.y * 64;
    const int tc = threadIdx.x & 63, tr = threadIdx.x >> 6;
    for (int r = tr; r < 64; r += 4) {
        const int k = k0 + r, n = n0 + tc;
        T[r][tc] = (k < K && n < N) ? W[(size_t)k * N + n] : 0.0f;
    }
    __syncthreads();
    for (int r = tr; r < 64; r += 4) {
        const int n = n0 + r, k = k0 + tc;
        if (n < N && k < K) {
            f16 h, l;
            fsplit(T[tc][r], h, l);
            Th[(size_t)n * K + k] = h;
            Tl[(size_t)n * K + k] = l;
        }
    }
}

// ---------------------------------------------------------------------------
// Degree counts (float), then invert: c -> 1/max(c,1)   [round-2..4 validated]
// ---------------------------------------------------------------------------
__global__ __launch_bounds__(256) void count_kernel(
    const int* __restrict__ s, const int* __restrict__ o, float* __restrict__ cnt)
{
    const int t = blockIdx.x * 256 + threadIdx.x;
    if (t < NTRI) {
        atomicAdd(&cnt[s[t]], 1.0f);
        atomicAdd(&cnt[o[t]], 1.0f);
    }
}

__global__ __launch_bounds__(256) void invcnt_kernel(float* __restrict__ cnt)
{
    const int i = blockIdx.x * 256 + threadIdx.x;
    if (i < NOBJ) cnt[i] = 1.0f / fmaxf(cnt[i], 1.0f);
}

enum { AM_PLAIN = 0, AM_GATHER = 1, AM_SCALED = 2 };
enum { EP_STORE = 0, EP_SPLIT = 1, EP_STORE16 = 2 };

// ---------------------------------------------------------------------------
// Split-f16 MFMA GEMM, global_load_lds staging, linear LDS [128][32] f16.
// Round-4 structure (passed on HW). Pred operand: hi f16 + lo e5m2 byte
// (decoded in staging); pred outputs stored as hi f16 + e5m2 lo.
// ---------------------------------------------------------------------------
template <int AMODE, int EPMODE, int DIN, int K, int H, int DOUT, int NTOT, int PRED32>
__global__ __launch_bounds__(256, 2) void mgemm_kernel(
    const f16* __restrict__ A0h, const f16* __restrict__ A0l,    // obj (gather) or hid (plain)
    const f16* __restrict__ A1h, const uint8_t* __restrict__ A1q,// pred hi f16 / lo e5m2 (layers>=1)
    const float* __restrict__ A1f,                               // pred f32 (layer 0)
    const int* __restrict__ sidx, const int* __restrict__ oidx,
    const f16* __restrict__ Bth, const f16* __restrict__ Btl,    // Wt [NTOT][K]
    const float* __restrict__ bias,
    float* __restrict__ C0,                                      // EP_SPLIT: pooled (atomics)
    f16* __restrict__ D0h, f16* __restrict__ D0l,                // EP_STORE: hid hi/lo
    uint8_t* __restrict__ D0q,                                   // EP_SPLIT: pred lo out
    int M)
{
    __shared__ f16 Ah[128][32], Al[128][32], Bh[128][32], Bl[128][32];
    __shared__ int sIdxL[128], oIdxL[128];

    const int tid = threadIdx.x;
    const int wave = tid >> 6, lane = tid & 63;
    const int l16 = lane & 15, lq = lane >> 4;
    const int m0 = blockIdx.x * 128, n0 = blockIdx.y * 128;
    const int wr = (wave >> 1) * 64, wc = (wave & 1) * 64;

    if (AMODE == AM_GATHER) {
        if (tid < 128) {
            int rr = m0 + tid;
            if (rr > M - 1) rr = M - 1;
            sIdxL[tid] = sidx[rr];
            oIdxL[tid] = oidx[rr];
        }
        __syncthreads();
    }

    const int rA0 = wave * 16 + (lane >> 2);
    const int rA1 = 64 + wave * 16 + (lane >> 2);
    const int cc  = (lane & 3) * 8;
    int gA0 = m0 + rA0; if (gA0 > M - 1) gA0 = M - 1;
    int gA1 = m0 + rA1; if (gA1 > M - 1) gA1 = M - 1;

    const f16 *aSh0 = nullptr, *aSl0 = nullptr, *aSh1 = nullptr, *aSl1 = nullptr;
    const f16 *aOh0 = nullptr, *aOl0 = nullptr, *aOh1 = nullptr, *aOl1 = nullptr;
    const f16 *aPh0 = nullptr, *aPh1 = nullptr;
    const uint8_t *aPq0 = nullptr, *aPq1 = nullptr;
    const float* pf = nullptr;
    if (AMODE == AM_GATHER) {
        const int s0 = sIdxL[rA0], s1 = sIdxL[rA1];
        const int o0 = oIdxL[rA0], o1 = oIdxL[rA1];
        aSh0 = A0h + (size_t)s0 * DIN + cc;  aSl0 = A0l + (size_t)s0 * DIN + cc;
        aSh1 = A0h + (size_t)s1 * DIN + cc;  aSl1 = A0l + (size_t)s1 * DIN + cc;
        aOh0 = A0h + (size_t)o0 * DIN + cc;  aOl0 = A0l + (size_t)o0 * DIN + cc;
        aOh1 = A0h + (size_t)o1 * DIN + cc;  aOl1 = A0l + (size_t)o1 * DIN + cc;
        if (PRED32) {
            int gw = m0 + (tid >> 1);
            if (gw > M - 1) gw = M - 1;
            pf = A1f + (size_t)gw * DIN + (tid & 1) * 16;
        } else {
            aPh0 = A1h + (size_t)gA0 * DIN + cc;  aPq0 = A1q + (size_t)gA0 * DIN + cc;
            aPh1 = A1h + (size_t)gA1 * DIN + cc;  aPq1 = A1q + (size_t)gA1 * DIN + cc;
        }
    } else {
        aSh0 = A0h + (size_t)gA0 * K + cc;  aSl0 = A0l + (size_t)gA0 * K + cc;
        aSh1 = A0h + (size_t)gA1 * K + cc;  aSl1 = A0l + (size_t)gA1 * K + cc;
    }
    const f16* bH0 = Bth + (size_t)(n0 + rA0) * K + cc;
    const f16* bH1 = Bth + (size_t)(n0 + rA1) * K + cc;
    const f16* bL0 = Btl + (size_t)(n0 + rA0) * K + cc;
    const f16* bL1 = Btl + (size_t)(n0 + rA1) * K + cc;

    f32x4 acc[4][4];
    const f32x4 zz = {0.0f, 0.0f, 0.0f, 0.0f};
#pragma unroll
    for (int i = 0; i < 4; ++i)
#pragma unroll
        for (int j = 0; j < 4; ++j) acc[i][j] = zz;

#pragma unroll 1
    for (int k0 = 0; k0 < K; k0 += 32) {
        // ---- stage A ----
        if (AMODE == AM_GATHER && k0 >= DIN && k0 < 2 * DIN) {
            if (PRED32) {
                // f32 pred region (layer 0): reg-convert + ds_write
                const int arowW = tid >> 1;
                const int koffW = (tid & 1) * 16;
                const float* src = pf + (k0 - DIN);
                float v[16];
#pragma unroll
                for (int q = 0; q < 4; ++q)
                    *reinterpret_cast<float4*>(&v[q * 4]) = *reinterpret_cast<const float4*>(src + q * 4);
                f16 hh[16], ll[16];
#pragma unroll
                for (int e = 0; e < 16; ++e) fsplit(v[e], hh[e], ll[e]);
                *reinterpret_cast<f16x8*>(&Ah[arowW][koffW])     = *reinterpret_cast<f16x8*>(&hh[0]);
                *reinterpret_cast<f16x8*>(&Ah[arowW][koffW + 8]) = *reinterpret_cast<f16x8*>(&hh[8]);
                *reinterpret_cast<f16x8*>(&Al[arowW][koffW])     = *reinterpret_cast<f16x8*>(&ll[0]);
                *reinterpret_cast<f16x8*>(&Al[arowW][koffW + 8]) = *reinterpret_cast<f16x8*>(&ll[8]);
            } else {
                // pred region: hi via gl_lds16, lo via e5m2 decode + ds_write
                const int off = k0 - DIN;
                gl_lds16(aPh0 + off, &Ah[wave * 16][0]);
                gl_lds16(aPh1 + off, &Ah[64 + wave * 16][0]);
                const uint2 q0 = *reinterpret_cast<const uint2*>(aPq0 + off);
                const uint2 q1 = *reinterpret_cast<const uint2*>(aPq1 + off);
                *reinterpret_cast<f16x8*>(&Al[rA0][cc]) = e5m2x8_to_f16x8(q0.x, q0.y);
                *reinterpret_cast<f16x8*>(&Al[rA1][cc]) = e5m2x8_to_f16x8(q1.x, q1.y);
            }
        } else {
            const f16 *sh0, *sl0, *sh1, *sl1;
            int off;
            if (AMODE != AM_GATHER) {
                sh0 = aSh0; sl0 = aSl0; sh1 = aSh1; sl1 = aSl1; off = k0;
            } else if (k0 < DIN) {
                sh0 = aSh0; sl0 = aSl0; sh1 = aSh1; sl1 = aSl1; off = k0;
            } else {
                sh0 = aOh0; sl0 = aOl0; sh1 = aOh1; sl1 = aOl1; off = k0 - 2 * DIN;
            }
            gl_lds16(sh0 + off, &Ah[wave * 16][0]);
            gl_lds16(sh1 + off, &Ah[64 + wave * 16][0]);
            gl_lds16(sl0 + off, &Al[wave * 16][0]);
            gl_lds16(sl1 + off, &Al[64 + wave * 16][0]);
        }
        // ---- stage B ----
        gl_lds16(bH0 + k0, &Bh[wave * 16][0]);
        gl_lds16(bH1 + k0, &Bh[64 + wave * 16][0]);
        gl_lds16(bL0 + k0, &Bl[wave * 16][0]);
        gl_lds16(bL1 + k0, &Bl[64 + wave * 16][0]);
        __syncthreads();
        // ---- fragments + MFMA ----
        f16x8 fah[4], fal[4], fbh[4], fbl[4];
#pragma unroll
        for (int fi = 0; fi < 4; ++fi) {
            const int r = wr + fi * 16 + l16;
            fah[fi] = *reinterpret_cast<const f16x8*>(&Ah[r][lq * 8]);
            fal[fi] = *reinterpret_cast<const f16x8*>(&Al[r][lq * 8]);
        }
#pragma unroll
        for (int fj = 0; fj < 4; ++fj) {
            const int c = wc + fj * 16 + l16;
            fbh[fj] = *reinterpret_cast<const f16x8*>(&Bh[c][lq * 8]);
            fbl[fj] = *reinterpret_cast<const f16x8*>(&Bl[c][lq * 8]);
        }
#pragma unroll
        for (int fi = 0; fi < 4; ++fi)
#pragma unroll
            for (int fj = 0; fj < 4; ++fj) {
                acc[fi][fj] = __builtin_amdgcn_mfma_f32_16x16x32_f16(fah[fi], fbh[fj], acc[fi][fj], 0, 0, 0);
                acc[fi][fj] = __builtin_amdgcn_mfma_f32_16x16x32_f16(fah[fi], fbl[fj], acc[fi][fj], 0, 0, 0);
                acc[fi][fj] = __builtin_amdgcn_mfma_f32_16x16x32_f16(fal[fi], fbh[fj], acc[fi][fj], 0, 0, 0);
            }
        __syncthreads();
    }

    // ---- epilogue ----
    float bb[4];
#pragma unroll
    for (int fj = 0; fj < 4; ++fj) bb[fj] = bias[n0 + wc + fj * 16 + l16];

    if (EPMODE == EP_STORE) {
#pragma unroll
        for (int fi = 0; fi < 4; ++fi)
#pragma unroll
            for (int r = 0; r < 4; ++r) {
                const int rowg = m0 + wr + fi * 16 + lq * 4 + r;
                if (rowg >= M) continue;
#pragma unroll
                for (int fj = 0; fj < 4; ++fj) {
                    const int col = n0 + wc + fj * 16 + l16;
                    f16 h, l;
                    fsplit(leaky(acc[fi][fj][r] + bb[fj]), h, l);
                    D0h[(size_t)rowg * NTOT + col] = h;
                    D0l[(size_t)rowg * NTOT + col] = l;
                }
            }
    } else {
        constexpr int SCH = H / 128;
        const int chunk = blockIdx.y;
#pragma unroll
        for (int fi = 0; fi < 4; ++fi)
#pragma unroll
            for (int r = 0; r < 4; ++r) {
                const int rowg = m0 + wr + fi * 16 + lq * 4 + r;
                if (rowg >= M) continue;
                if (chunk < SCH) {
                    const int t = sidx[rowg];
                    float* dst = C0 + (size_t)t * H;
#pragma unroll
                    for (int fj = 0; fj < 4; ++fj) {
                        const int col = n0 + wc + fj * 16 + l16;
                        atomicAdd(dst + col, leaky(acc[fi][fj][r] + bb[fj]));
                    }
                } else if (chunk == SCH) {
#pragma unroll
                    for (int fj = 0; fj < 4; ++fj) {
                        const int col = n0 + wc + fj * 16 + l16 - H;
                        const float y = leaky(acc[fi][fj][r] + bb[fj]);
                        f16 h, l;
                        fsplit(y, h, l);
                        D0h[(size_t)rowg * DOUT + col] = h;
                        D0q[(size_t)rowg * DOUT + col] = f16_to_e5m2(l);
                    }
                } else {
                    const int t = oidx[rowg];
                    float* dst = C0 + (size_t)t * H;
#pragma unroll
                    for (int fj = 0; fj < 4; ++fj) {
                        const int col = n0 + wc + fj * 16 + l16 - H - DOUT;
                        atomicAdd(dst + col, leaky(acc[fi][fj][r] + bb[fj]));
                    }
                }
            }
    }
}

// ---------------------------------------------------------------------------
// f32 SGEMM for the node path (8% of FLOPs) — round-4 validated.
// ---------------------------------------------------------------------------
template <int AMODE, int EPMODE, int K, int NTOT>
__global__ __launch_bounds__(256, 2) void sgemm_kernel(
    const float* __restrict__ A0, const float* __restrict__ scale,
    const float* __restrict__ W, const float* __restrict__ bias,
    float* __restrict__ C0, f16* __restrict__ C16h, f16* __restrict__ C16l,
    int M)
{
    constexpr int BM = 128, BN = 128, KB = 32;
    __shared__ float As[KB][BM + 4];
    __shared__ float Bs[KB][BN + 4];

    const int tid = threadIdx.x;
    const int tx = tid & 15;
    const int ty = tid >> 4;
    const int m0 = blockIdx.x * BM;
    const int n0 = blockIdx.y * BN;

    float acc[8][8];
#pragma unroll
    for (int i = 0; i < 8; ++i)
#pragma unroll
        for (int j = 0; j < 8; ++j) acc[i][j] = 0.0f;

    const int arow = tid >> 1;
    const int akb  = (tid & 1) * 16;
    int am = m0 + arow;
    if (am > M - 1) am = M - 1;
    const int bkr = tid >> 5;
    const int bn  = (tid & 31) * 4;
    float ascale = 1.0f;
    if (AMODE == AM_SCALED) ascale = scale[am];

#pragma unroll 1
    for (int k0 = 0; k0 < K; k0 += KB) {
        __syncthreads();
        const float* src = A0 + (size_t)am * K + k0;
#pragma unroll
        for (int q = 0; q < 4; ++q) {
            float4 v = *reinterpret_cast<const float4*>(src + akb + q * 4);
            if (AMODE == AM_SCALED) { v.x *= ascale; v.y *= ascale; v.z *= ascale; v.w *= ascale; }
            const int lk = akb + q * 4;
            As[lk + 0][arow] = v.x;
            As[lk + 1][arow] = v.y;
            As[lk + 2][arow] = v.z;
            As[lk + 3][arow] = v.w;
        }
#pragma unroll
        for (int q = 0; q < 4; ++q) {
            const int kr = bkr + q * 8;
            const float4 v = *reinterpret_cast<const float4*>(W + (size_t)(k0 + kr) * NTOT + n0 + bn);
            *reinterpret_cast<float4*>(&Bs[kr][bn]) = v;
        }
        __syncthreads();
#pragma unroll
        for (int kk = 0; kk < KB; ++kk) {
            float a[8], b[8];
            *reinterpret_cast<float4*>(&a[0]) = *reinterpret_cast<const float4*>(&As[kk][ty * 8]);
            *reinterpret_cast<float4*>(&a[4]) = *reinterpret_cast<const float4*>(&As[kk][ty * 8 + 4]);
            *reinterpret_cast<float4*>(&b[0]) = *reinterpret_cast<const float4*>(&Bs[kk][tx * 4]);
            *reinterpret_cast<float4*>(&b[4]) = *reinterpret_cast<const float4*>(&Bs[kk][64 + tx * 4]);
#pragma unroll
            for (int i = 0; i < 8; ++i)
#pragma unroll
                for (int j = 0; j < 8; ++j)
                    acc[i][j] = fmaf(a[i], b[j], acc[i][j]);
        }
    }

    float bv[8];
#pragma unroll
    for (int j = 0; j < 4; ++j) {
        bv[j]     = bias[n0 + tx * 4 + j];
        bv[4 + j] = bias[n0 + 64 + tx * 4 + j];
    }

#pragma unroll
    for (int i = 0; i < 8; ++i) {
        const int r = m0 + ty * 8 + i;
        if (r >= M) continue;
        if (EPMODE == EP_STORE) {
            float4 v0, v1;
            v0.x = leaky(acc[i][0] + bv[0]);
            v0.y = leaky(acc[i][1] + bv[1]);
            v0.z = leaky(acc[i][2] + bv[2]);
            v0.w = leaky(acc[i][3] + bv[3]);
            v1.x = leaky(acc[i][4] + bv[4]);
            v1.y = leaky(acc[i][5] + bv[5]);
            v1.z = leaky(acc[i][6] + bv[6]);
            v1.w = leaky(acc[i][7] + bv[7]);
            *reinterpret_cast<float4*>(&C0[(size_t)r * NTOT + n0 + tx * 4])      = v0;
            *reinterpret_cast<float4*>(&C0[(size_t)r * NTOT + n0 + 64 + tx * 4]) = v1;
        } else {
#pragma unroll
            for (int j = 0; j < 8; ++j) {
                const int col = n0 + (j < 4 ? tx * 4 + j : 64 + tx * 4 + (j - 4));
                f16 h, l;
                fsplit(leaky(acc[i][j] + bv[j]), h, l);
                C16h[(size_t)r * NTOT + col] = h;
                C16l[(size_t)r * NTOT + col] = l;
            }
        }
    }
}

// ---------------------------------------------------------------------------
// Final: out = leaky((obj_hi + obj_lo) @ W_bb + b_bb)
// ---------------------------------------------------------------------------
__global__ __launch_bounds__(256) void final_kernel(
    const f16* __restrict__ oh, const f16* __restrict__ ol,
    const float* __restrict__ W, const float* __restrict__ b, float* __restrict__ out)
{
    __shared__ float Ws[128 * 4];
    const int tid = threadIdx.x;
    for (int i = tid; i < 512; i += 256) Ws[i] = W[i];
    __syncthreads();
    const int r = blockIdx.x * 256 + tid;
    if (r >= NOBJ) return;
    float a0 = b[0], a1 = b[1], a2 = b[2], a3 = b[3];
    const f16* __restrict__ ph = oh + (size_t)r * 128;
    const f16* __restrict__ pl = ol + (size_t)r * 128;
#pragma unroll 4
    for (int k = 0; k < 128; k += 8) {
        const f16x8 hv = *reinterpret_cast<const f16x8*>(ph + k);
        const f16x8 lv = *reinterpret_cast<const f16x8*>(pl + k);
#pragma unroll
        for (int e = 0; e < 8; ++e) {
            const float x = (float)hv[e] + (float)lv[e];
            a0 = fmaf(x, Ws[(k + e) * 4 + 0], a0);
            a1 = fmaf(x, Ws[(k + e) * 4 + 1], a1);
            a2 = fmaf(x, Ws[(k + e) * 4 + 2], a2);
            a3 = fmaf(x, Ws[(k + e) * 4 + 3], a3);
        }
    }
    float4 o;
    o.x = leaky(a0);
    o.y = leaky(a1);
    o.z = leaky(a2);
    o.w = leaky(a3);
    *reinterpret_cast<float4*>(out + (size_t)r * 4) = o;
}

// ---------------------------------------------------------------------------
// Host orchestration. Fixed footprint ~233.6 MB (fits the inferred 256 MiB
// d_ws with ~34.8 MB scratch -> CH ~16896, 15 edge chunks, full occupancy).
// ---------------------------------------------------------------------------
extern "C" void kernel_launch(void* const* d_in, const int* in_sizes, int n_in,
                              void* d_out, int out_size, void* d_ws, size_t ws_size,
                              hipStream_t stream)
{
    const float* obj_vecs   = (const float*)d_in[0];
    const float* pred_vecs  = (const float*)d_in[1];
    const float* pred_boxes = (const float*)d_in[2];
    const int*   s_idx      = (const int*)d_in[3];
    const int*   o_idx      = (const int*)d_in[4];
    const float* W_emb      = (const float*)d_in[5];
    const float* b_emb      = (const float*)d_in[6];
    const float* W_bb       = (const float*)d_in[39];
    const float* b_bb       = (const float*)d_in[40];
    auto LP = [&](int layer, int which) -> const float* {
        return (const float*)d_in[7 + layer * 8 + which];
    };

    uint8_t* p = (uint8_t*)d_ws;
    auto take = [&](size_t bytes) -> void* {
        void* r = (void*)p;
        p += (bytes + 255) & ~(size_t)255;
        return r;
    };
    f16*     predh  = (f16*)take((size_t)NTRI * 128 * 2);      // 64.0 MB
    uint8_t* predq  = (uint8_t*)take((size_t)NTRI * 128);      // 32.0 MB (e5m2 lo)
    float*   pooled = (float*)take((size_t)NOBJ * 512 * 4);    // 102.4 MB
    f16*     objh   = (f16*)take((size_t)NOBJ * 128 * 2);      // 12.8 MB
    f16*     objl   = (f16*)take((size_t)NOBJ * 128 * 2);      // 12.8 MB
    float*   counts = (float*)take((size_t)NOBJ * 4);          // 0.2 MB

    const int K1[4] = {192, 384, 384, 384};
    const int N1[4] = {512, 512, 512, 128};
    const int K2[4] = {512, 512, 512, 128};
    const int N2[4] = {1152, 1152, 1152, 384};
    f16 *wah[4], *wal[4], *wbh[4], *wbl[4];
    for (int L = 0; L < 4; ++L) {
        wah[L] = (f16*)take((size_t)N1[L] * K1[L] * 2);
        wal[L] = (f16*)take((size_t)N1[L] * K1[L] * 2);
        wbh[L] = (f16*)take((size_t)N2[L] * K2[L] * 2);
        wbl[L] = (f16*)take((size_t)N2[L] * K2[L] * 2);
    }
    const size_t used = (size_t)(p - (uint8_t*)d_ws);
    const size_t rem = ws_size > used ? ws_size - used : 0;
    // scratch per chunk-row: hid hi/lo = 512*2*2 B = 2048 B (node f32 hid aliases it)
    long long ch = (long long)(rem / 2048);
    if (ch > 50176) ch = 50176;
    if (ch > 256)   ch = (ch / 128) * 128;
    if (ch < 1)     ch = 1;
    const int CH = (int)ch;
    f16*   hidh = (f16*)p;
    f16*   hidl = hidh + (size_t)CH * 512;
    float* scrF = (float*)hidh;   // node hid (time-shared, same byte span)

    const dim3 blk(256);

    // ---- prep ----
    hipMemsetAsync(counts, 0, NOBJ * sizeof(float), stream);
    embed_kernel<<<(NOBJ + 3) / 4, blk, 0, stream>>>(obj_vecs, pred_boxes, W_emb, b_emb, objh, objl);
    count_kernel<<<(NTRI + 255) / 256, blk, 0, stream>>>(s_idx, o_idx, counts);
    invcnt_kernel<<<(NOBJ + 255) / 256, blk, 0, stream>>>(counts);
    for (int L = 0; L < 4; ++L) {
        tsplit_kernel<<<dim3(N1[L] / 64, K1[L] / 64), blk, 0, stream>>>(LP(L, 0), K1[L], N1[L], wah[L], wal[L]);
        tsplit_kernel<<<dim3(N2[L] / 64, K2[L] / 64), blk, 0, stream>>>(LP(L, 2), K2[L], N2[L], wbh[L], wbl[L]);
    }

    // ---------------- layer 0: DIN=64, K1=192, H=512, DOUT=128 ----------------
    hipMemsetAsync(pooled, 0, (size_t)NOBJ * 512 * sizeof(float), stream);
    for (int r0 = 0; r0 < NTRI; r0 += CH) {
        const int CM = (NTRI - r0 < CH) ? (NTRI - r0) : CH;
        const int mt = (CM + 127) / 128;
        mgemm_kernel<AM_GATHER, EP_STORE, 64, 192, 512, 128, 512, 1><<<dim3(mt, 4), blk, 0, stream>>>(
            objh, objl, nullptr, nullptr, pred_vecs + (size_t)r0 * 64,
            s_idx + r0, o_idx + r0, wah[0], wal[0], LP(0, 1), nullptr, hidh, hidl, nullptr, CM);
        mgemm_kernel<AM_PLAIN, EP_SPLIT, 0, 512, 512, 128, 1152, 0><<<dim3(mt, 9), blk, 0, stream>>>(
            hidh, hidl, nullptr, nullptr, nullptr,
            s_idx + r0, o_idx + r0, wbh[0], wbl[0], LP(0, 3), pooled,
            predh + (size_t)r0 * 128, nullptr, predq + (size_t)r0 * 128, CM);
    }
    for (int r0 = 0; r0 < NOBJ; r0 += CH) {
        const int CM = (NOBJ - r0 < CH) ? (NOBJ - r0) : CH;
        const int mt = (CM + 127) / 128;
        sgemm_kernel<AM_SCALED, EP_STORE, 512, 512><<<dim3(mt, 4), blk, 0, stream>>>(
            pooled + (size_t)r0 * 512, counts + r0, LP(0, 4), LP(0, 5), scrF, nullptr, nullptr, CM);
        sgemm_kernel<AM_PLAIN, EP_STORE16, 512, 128><<<dim3(mt, 1), blk, 0, stream>>>(
            scrF, nullptr, LP(0, 6), LP(0, 7), nullptr, objh + (size_t)r0 * 128, objl + (size_t)r0 * 128, CM);
    }

    // ---------------- layers 1,2: DIN=128, K1=384, H=512, DOUT=128 ----------------
    for (int L = 1; L <= 2; ++L) {
        hipMemsetAsync(pooled, 0, (size_t)NOBJ * 512 * sizeof(float), stream);
        for (int r0 = 0; r0 < NTRI; r0 += CH) {
            const int CM = (NTRI - r0 < CH) ? (NTRI - r0) : CH;
            const int mt = (CM + 127) / 128;
            mgemm_kernel<AM_GATHER, EP_STORE, 128, 384, 512, 128, 512, 0><<<dim3(mt, 4), blk, 0, stream>>>(
                objh, objl, predh + (size_t)r0 * 128, predq + (size_t)r0 * 128, nullptr,
                s_idx + r0, o_idx + r0, wah[L], wal[L], LP(L, 1), nullptr, hidh, hidl, nullptr, CM);
            mgemm_kernel<AM_PLAIN, EP_SPLIT, 0, 512, 512, 128, 1152, 0><<<dim3(mt, 9), blk, 0, stream>>>(
                hidh, hidl, nullptr, nullptr, nullptr,
                s_idx + r0, o_idx + r0, wbh[L], wbl[L], LP(L, 3), pooled,
                predh + (size_t)r0 * 128, nullptr, predq + (size_t)r0 * 128, CM);
        }
        for (int r0 = 0; r0 < NOBJ; r0 += CH) {
            const int CM = (NOBJ - r0 < CH) ? (NOBJ - r0) : CH;
            const int mt = (CM + 127) / 128;
            sgemm_kernel<AM_SCALED, EP_STORE, 512, 512><<<dim3(mt, 4), blk, 0, stream>>>(
                pooled + (size_t)r0 * 512, counts + r0, LP(L, 4), LP(L, 5), scrF, nullptr, nullptr, CM);
            sgemm_kernel<AM_PLAIN, EP_STORE16, 512, 128><<<dim3(mt, 1), blk, 0, stream>>>(
                scrF, nullptr, LP(L, 6), LP(L, 7), nullptr, objh + (size_t)r0 * 128, objl + (size_t)r0 * 128, CM);
        }
    }

    // ---------------- layer 3: DIN=128, K1=384, H=128, DOUT=128 ----------------
    hipMemsetAsync(pooled, 0, (size_t)NOBJ * 128 * sizeof(float), stream);
    for (int r0 = 0; r0 < NTRI; r0 += CH) {
        const int CM = (NTRI - r0 < CH) ? (NTRI - r0) : CH;
        const int mt = (CM + 127) / 128;
        mgemm_kernel<AM_GATHER, EP_STORE, 128, 384, 128, 128, 128, 0><<<dim3(mt, 1), blk, 0, stream>>>(
            objh, objl, predh + (size_t)r0 * 128, predq + (size_t)r0 * 128, nullptr,
            s_idx + r0, o_idx + r0, wah[3], wal[3], LP(3, 1), nullptr, hidh, hidl, nullptr, CM);
        mgemm_kernel<AM_PLAIN, EP_SPLIT, 0, 128, 128, 128, 384, 0><<<dim3(mt, 3), blk, 0, stream>>>(
            hidh, hidl, nullptr, nullptr, nullptr,
            s_idx + r0, o_idx + r0, wbh[3], wbl[3], LP(3, 3), pooled,
            predh + (size_t)r0 * 128, nullptr, predq + (size_t)r0 * 128, CM);
    }
    for (int r0 = 0; r0 < NOBJ; r0 += CH) {
        const int CM = (NOBJ - r0 < CH) ? (NOBJ - r0) : CH;
        const int mt = (CM + 127) / 128;
        sgemm_kernel<AM_SCALED, EP_STORE, 128, 128><<<dim3(mt, 1), blk, 0, stream>>>(
            pooled + (size_t)r0 * 128, counts + r0, LP(3, 4), LP(3, 5), scrF, nullptr, nullptr, CM);
        sgemm_kernel<AM_PLAIN, EP_STORE16, 128, 128><<<dim3(mt, 1), blk, 0, stream>>>(
            scrF, nullptr, LP(3, 6), LP(3, 7), nullptr, objh + (size_t)r0 * 128, objl + (size_t)r0 * 128, CM);
    }

    final_kernel<<<(NOBJ + 255) / 256, blk, 0, stream>>>(objh, objl, W_bb, b_bb, (float*)d_out);
}